// Round 3
// baseline (226.726 us; speedup 1.0000x reference)
//
#include <hip/hip_runtime.h>

// Problem constants (fixed by the reference):
//   state_sequence [B=16, S=128, H=128, W=128] f32; N=32 objects; D=128.
//   T = 127; off-diagonal pairs = 992; out = [1024 cm] ++ [127*992*3 preds].
#define NPAIR 992
#define TSTEPS 127
#define NCOLB 256        // 65536 float4-columns / 256 threads per block
#define NSPLIT 4         // frame-range splits per column
#define SLOTS (NSPLIT * 32)   // 128 (t-slot rows in `partial`)

// ---------------- k_scan: the 134 MB streaming reduction ----------------
// Grid 1024 = NCOLB x NSPLIT, block 256 (4 waves). Each thread owns one
// float4 column over a 33-frame window; per step, wave-OR via shfl, result
// to the wave's own LDS slot (no atomics), block-OR'd into
// partial[colblk][slot] (256B contiguous store per block).
__device__ __forceinline__ void step_fn(int4 a, int4 b, int tl, int wv,
                                        unsigned long long (*part)[32]) {
  unsigned m = (1u << (a.x & 31)) | (1u << (a.y & 31)) |
               (1u << (a.z & 31)) | (1u << (a.w & 31));
  bool h0 = (a.x == b.x) || (a.y == b.y) || (a.z == b.z) || (a.w == b.w);
  bool h1 = (a.x != b.x) || (a.y != b.y) || (a.z != b.z) || (a.w != b.w);
#pragma unroll
  for (int o = 32; o; o >>= 1) m |= __shfl_xor(m, o);
  unsigned long long v = m;
  if (__any(h0 ? 1 : 0)) v |= (1ull << 32);
  if (__any(h1 ? 1 : 0)) v |= (1ull << 33);
  if ((threadIdx.x & 63) == 0) part[wv][tl] = v;
}

__global__ __launch_bounds__(256) void k_scan(const float* __restrict__ st,
                                              unsigned long long* __restrict__ partial) {
  __shared__ unsigned long long part[4][32];
  int s   = blockIdx.x & 3;          // frame-range split
  int cb  = blockIdx.x >> 2;         // column-block 0..255
  int tid = threadIdx.x;
  int wv  = tid >> 6;
  int q   = cb * 256 + tid;          // float4 column id, 0..65535
  int b   = q >> 12;                 // batch (4096 float4 cols per frame)
  int c4  = q & 4095;
  int t0  = (s == 3) ? 95 : 32 * s;  // steps t0..t0+31 (t=95 done twice, OR-idempotent)
  const float4* p4 = (const float4*)st;
  size_t base = ((size_t)b * 128 + t0) * 4096 + c4;   // frame f at base + (f-t0)*4096

  float4 f0 = p4[base];
  int4 prev = {(int)f0.x, (int)f0.y, (int)f0.z, (int)f0.w};
  for (int ch = 0; ch < 4; ++ch) {   // 4 chunks x 8 frames, 8 loads in flight
    float4 g[8];
#pragma unroll
    for (int u = 0; u < 8; ++u) g[u] = p4[base + (size_t)(ch * 8 + 1 + u) * 4096];
    int4 n[8];
#pragma unroll
    for (int u = 0; u < 8; ++u) {
      n[u].x = (int)g[u].x; n[u].y = (int)g[u].y;
      n[u].z = (int)g[u].z; n[u].w = (int)g[u].w;
    }
    step_fn(prev, n[0], ch * 8 + 0, wv, part);
#pragma unroll
    for (int u = 0; u < 7; ++u) step_fn(n[u], n[u + 1], ch * 8 + 1 + u, wv, part);
    prev = n[7];
  }
  __syncthreads();
  if (tid < 32) {
    unsigned long long v = part[0][tid] | part[1][tid] | part[2][tid] | part[3][tid];
    partial[(size_t)cb * SLOTS + s * 32 + tid] = v;   // 256B contiguous per block
  }
}

// ---------------- k_cm: reduce partials, then sigmoid(cm + inc) ----------
// Slot->t mapping: slot<95 -> t=slot; slots 95,96 -> t=95; slot>96 -> t=slot-1.
__global__ __launch_bounds__(1024) void k_cm(const unsigned long long* __restrict__ partial,
                                             const float* __restrict__ cmin,
                                             float* __restrict__ out) {
  __shared__ unsigned long long G[SLOTS][9];   // col 8 holds per-slot OR
  __shared__ unsigned long long F[TSTEPS];
  int tid  = threadIdx.x;
  int slot = tid & 127, c = tid >> 7;          // 128 slots x 8 chunks
  unsigned long long v = 0;
#pragma unroll 4
  for (int k = 0; k < 32; ++k) v |= partial[(size_t)(c * 32 + k) * SLOTS + slot];
  G[slot][c] = v;
  __syncthreads();
  if (tid < SLOTS) {
    G[tid][8] = G[tid][0] | G[tid][1] | G[tid][2] | G[tid][3] |
                G[tid][4] | G[tid][5] | G[tid][6] | G[tid][7];
  }
  __syncthreads();
  if (tid < TSTEPS) {
    F[tid] = (tid < 95) ? G[tid][8]
           : (tid == 95 ? (G[95][8] | G[96][8]) : G[tid + 1][8]);
  }
  __syncthreads();
  int i = tid >> 5, j = tid & 31;
  float inc = 0.0f;
  if (j < 2 && i != j) {
    int cnt = 0;
#pragma unroll 1
    for (int t = 0; t < TSTEPS; ++t) {
      unsigned long long f = F[t];
      cnt += (int)(((f >> i) & 1ull) & ((f >> (32 + j)) & 1ull));
    }
    inc = 0.01f * (float)cnt;
  }
  float val = cmin[tid] + inc;
  out[tid] = 1.0f / (1.0f + expf(-val));
}

// ---------------- k_ab: A[i][h] = emb[i]·W1[0:128,h], B[i][h] = emb[i]·W1[128:256,h]
// Lane-wise the W1 row read is already coalesced (512B/row across 128 lanes).
__global__ __launch_bounds__(128) void k_ab(const float* __restrict__ emb,
                                            const float* __restrict__ W1,
                                            float* __restrict__ AB) {
  int blk = blockIdx.x;            // 0..63 ; sel = blk/32, i = blk%32
  int sel = blk >> 5, i = blk & 31;
  int h = threadIdx.x;
  __shared__ float e[128];
  e[h] = emb[i * 128 + h];
  __syncthreads();
  const float* w = W1 + (size_t)sel * 128 * 128;
  float acc = 0.0f;
#pragma unroll 8
  for (int k = 0; k < 128; ++k) acc += e[k] * w[k * 128 + h];
  AB[blk * 128 + h] = acc;         // AB[sel*32+i][h]
}

// ---------------- k_pp: per off-diagonal pair, mech + direct pred writes ----
__global__ __launch_bounds__(128) void k_pp(const float* __restrict__ AB,
                                            const float* __restrict__ b1,
                                            const float* __restrict__ W2,
                                            const float* __restrict__ b2,
                                            float* __restrict__ outp) {
  int p = blockIdx.x;              // 0..991, i-major off-diagonal index
  int i = p / 31, r = p - i * 31;
  int j = r + (r >= i ? 1 : 0);
  int h = threadIdx.x;

  float hid = AB[i * 128 + h] + AB[(32 + j) * 128 + h] + b1[h];
  hid = fmaxf(hid, 0.0f);
  float m0 = hid * W2[h * 3 + 0];
  float m1 = hid * W2[h * 3 + 1];
  float m2 = hid * W2[h * 3 + 2];
#pragma unroll
  for (int o = 32; o; o >>= 1) {
    m0 += __shfl_xor(m0, o);
    m1 += __shfl_xor(m1, o);
    m2 += __shfl_xor(m2, o);
  }
  __shared__ float sred[2][3];
  if ((h & 63) == 0) { int w = h >> 6; sred[w][0] = m0; sred[w][1] = m1; sred[w][2] = m2; }
  __syncthreads();
  float e0 = sred[0][0] + sred[1][0] + b2[0];
  float e1 = sred[0][1] + sred[1][1] + b2[1];
  float e2 = sred[0][2] + sred[1][2] + b2[2];
  if (h < TSTEPS) {                // thread h writes preds for t = h
    size_t o_ = ((size_t)h * NPAIR + p) * 3;
    outp[o_] = e0; outp[o_ + 1] = e1; outp[o_ + 2] = e2;
  }
}

extern "C" void kernel_launch(void* const* d_in, const int* in_sizes, int n_in,
                              void* d_out, int out_size, void* d_ws, size_t ws_size,
                              hipStream_t stream) {
  const float* st   = (const float*)d_in[0];   // state_sequence [16,128,128,128]
  const float* emb  = (const float*)d_in[1];   // [32,128]
  const float* W1   = (const float*)d_in[2];   // [256,128]
  const float* b1   = (const float*)d_in[3];   // [128]
  const float* W2   = (const float*)d_in[4];   // [128,3]
  const float* b2   = (const float*)d_in[5];   // [3]
  const float* cmin = (const float*)d_in[6];   // [32,32]
  float* out = (float*)d_out;                  // [1024 cm] ++ [127*992*3 preds]

  // Workspace (every byte written before read; no init needed):
  unsigned long long* partial = (unsigned long long*)d_ws;       // 256*128*8 = 256 KB
  float* AB = (float*)((char*)d_ws + NCOLB * SLOTS * 8);         // 64*128*4  = 32 KB

  hipLaunchKernelGGL(k_ab,   dim3(64),              dim3(128),  0, stream, emb, W1, AB);
  hipLaunchKernelGGL(k_scan, dim3(NCOLB * NSPLIT),  dim3(256),  0, stream, st, partial);
  hipLaunchKernelGGL(k_cm,   dim3(1),               dim3(1024), 0, stream, partial, cmin, out);
  hipLaunchKernelGGL(k_pp,   dim3(NPAIR),           dim3(128),  0, stream, AB, b1, W2, b2, out + 1024);
}